// Round 3
// baseline (261.963 us; speedup 1.0000x reference)
//
#include <hip/hip_runtime.h>
#include <hip/hip_bf16.h>
#include <hip/hip_cooperative_groups.h>

namespace cg = cooperative_groups;

#define BB 8
#define NN 2048
#define VV 256
#define HH 1024
#define CHK 64
#define RPC 32
constexpr float EPS = 1e-5f;

typedef __attribute__((ext_vector_type(4))) float floatx4;
typedef __attribute__((ext_vector_type(8))) short short8;

__device__ __forceinline__ void load_lds16(const void* g, void* l) {
    __builtin_amdgcn_global_load_lds((const __attribute__((address_space(1))) void*)g,
                                     (__attribute__((address_space(3))) void*)l, 16, 0, 0);
}
__device__ __forceinline__ float bf16s_to_f(short s) {
    unsigned u = ((unsigned)(unsigned short)s) << 16;
    return __builtin_bit_cast(float, u);
}

// ---------------------------------------------------------------------------
// Single cooperative kernel. 256 blocks x 512 threads, 1 block/CU.
// Phase A (per block = 64 rows = 2 chunks of one batch; each 256-thread half
//   owns one chunk):
//   - redundant in-block LN of h[b,0,:] (attn+mlp) -> s0b, mlp row-0 swap
//   - bf16 convert of h (BOS swap), packed softmax weights {W0,WP-WZ,WZ,0},
//     chunk partial sums
//   - weight bf16 conversion (1 float4/thread: 256*512 = 2*H*V/4 exact)
//   - block 0 threads 0..255: v_bos = wo_w @ wv_bos
// grid.sync()  (device-scope release/acquire; replaces the launch boundary)
// Phase B (identical to verified mlp_fused5):
//   - exclusive chunk prefix from raw chunkSum partials (same c-order)
//   - double-buffered DMA-staged GEMM1/GEMM2 with XOR seg-swizzle
//   - epilogue: oacc -> LDS (stride 260), serial attention scan,
//     single out = attn + mlp store.
// ---------------------------------------------------------------------------
__global__ __launch_bounds__(512) void fused_all(
    const float* __restrict__ h,
    const float* __restrict__ g_attn, const float* __restrict__ b_attn,
    const float* __restrict__ g_mlp,  const float* __restrict__ b_mlp,
    const float* __restrict__ qk_dir,
    const float* __restrict__ wo_w,  const float* __restrict__ wv_bos,
    const float* __restrict__ wv,
    const float* __restrict__ qk_bos, const float* __restrict__ qk_prev,
    const float* __restrict__ w1, const float* __restrict__ w2,
    short* __restrict__ Xb,
    float* __restrict__ wpack,
    float* __restrict__ chunkSum,
    float* __restrict__ v_bos,
    short* __restrict__ w1b, short* __restrict__ w2b,
    float* __restrict__ out)
{
    __shared__ __align__(16) char smem[136 * 1024];
    // phase A views (dead before phase B's first LDS write)
    float (*lds8)[VV] = reinterpret_cast<float(*)[VV]>(smem);        // 8 KB
    float* mrow = reinterpret_cast<float*>(smem + 8 * VV * 4);       // 1 KB
    float* redA = mrow + VV;
    float* redB = redA + 8;
    float* redC = redB + 8;

    int tid  = threadIdx.x;
    int wave = tid >> 6, lane = tid & 63;
    int half = tid >> 8;          // 0/1 -> chunk within block
    int t256 = tid & 255;
    int m0 = blockIdx.x * 64;
    int b  = m0 >> 11;            // batch (2048 rows/batch)
    int n0 = m0 & (NN - 1);       // row offset within batch

    // ---- Phase A: LN of row 0 (both halves redundantly, wave-slot partials) ----
    float x0 = h[(size_t)b * NN * VV + t256];
    float s = x0;
    for (int off = 32; off > 0; off >>= 1) s += __shfl_down(s, off);
    if (lane == 0) redA[wave] = s;
    __syncthreads();
    float m = (redA[half * 4 + 0] + redA[half * 4 + 1] +
               redA[half * 4 + 2] + redA[half * 4 + 3]) * (1.0f / VV);
    float xc = x0 - m;
    float sv = xc * xc;
    for (int off = 32; off > 0; off >>= 1) sv += __shfl_down(sv, off);
    if (lane == 0) redB[wave] = sv;
    __syncthreads();
    float var = (redB[half * 4 + 0] + redB[half * 4 + 1] +
                 redB[half * 4 + 2] + redB[half * 4 + 3]) * (1.0f / VV);
    float inv = 1.0f / sqrtf(var + EPS);
    float an = xc * inv * g_attn[t256] + b_attn[t256];
    float mn = xc * inv * g_mlp[t256]  + b_mlp[t256];
    float sd = an * qk_dir[t256];
    for (int off = 32; off > 0; off >>= 1) sd += __shfl_down(sd, off);
    if (lane == 0) redC[wave] = sd;
    if (half == 0) mrow[t256] = mn;
    __syncthreads();
    float s0b = redC[half * 4 + 0] + redC[half * 4 + 1] +
                redC[half * 4 + 2] + redC[half * 4 + 3];

    // ---- Phase A: scan over this half's 32-row chunk (8 rows per wave) ----
    {
        int wave4 = wave & 3;
        int r0 = n0 + half * RPC + wave4 * 8;
        float4 wv4 = reinterpret_cast<const float4*>(wv)[lane];
        float4 qb4 = reinterpret_cast<const float4*>(qk_bos)[lane];
        float4 qp4 = reinterpret_cast<const float4*>(qk_prev)[lane];
        float4 vsum = {0.f, 0.f, 0.f, 0.f};
#pragma unroll
        for (int rr = 0; rr < 8; ++rr) {
            int r = r0 + rr;
            size_t base = ((size_t)b * NN + r) * VV;
            float4 x = *reinterpret_cast<const float4*>(h + base + lane * 4);
            float4 xs = x;
            if (r == 0) xs = *reinterpret_cast<const float4*>(&mrow[lane * 4]);
            __hip_bfloat16 c0 = __float2bfloat16(xs.x), c1 = __float2bfloat16(xs.y),
                           c2 = __float2bfloat16(xs.z), c3 = __float2bfloat16(xs.w);
            short4 pk;
            pk.x = *reinterpret_cast<short*>(&c0);
            pk.y = *reinterpret_cast<short*>(&c1);
            pk.z = *reinterpret_cast<short*>(&c2);
            pk.w = *reinterpret_cast<short*>(&c3);
            *reinterpret_cast<short4*>(Xb + base + lane * 4) = pk;
            if (r != 0) {
                vsum.x += bf16s_to_f(pk.x) * wv4.x; vsum.y += bf16s_to_f(pk.y) * wv4.y;
                vsum.z += bf16s_to_f(pk.z) * wv4.z; vsum.w += bf16s_to_f(pk.w) * wv4.w;
            }
            float s1 = x.x * qb4.x + x.y * qb4.y + x.z * qb4.z + x.w * qb4.w;
            float s2 = x.x * qp4.x + x.y * qp4.y + x.z * qp4.z + x.w * qp4.w;
            for (int off = 32; off > 0; off >>= 1) {
                s1 += __shfl_down(s1, off);
                s2 += __shfl_down(s2, off);
            }
            if (lane == 0) {
                int gid = b * NN + r;
                float W0, WP, WZ;
                if (r == 0) { W0 = 1.f; WP = 0.f; WZ = 0.f; }
                else if (r == 1) {
                    float a = s1 * s0b + s2;
                    float mm = fmaxf(a, 0.f);
                    float ea = expf(a - mm), ez = expf(-mm);
                    float Z = ea + ez;
                    W0 = ea / Z; WZ = ez / Z; WP = WZ;
                } else {
                    float a = s1 * s0b;
                    float mm = fmaxf(fmaxf(a, s2), 0.f);
                    float ea = expf(a - mm), ed = expf(s2 - mm), ez = expf(-mm);
                    float Z = ea + ed + (float)(r - 1) * ez;
                    W0 = ea / Z; WP = ed / Z; WZ = ez / Z;
                }
                float4 wp4 = {W0, WP - WZ, WZ, 0.f};
                *reinterpret_cast<float4*>(wpack + (size_t)gid * 4) = wp4;
            }
        }
        reinterpret_cast<float4*>(lds8[wave])[lane] = vsum;
    }

    // ---- Phase A: weight bf16 conversion (exact 1 float4 / thread) ----
    {
        int gi = blockIdx.x * 512 + tid;
        size_t off = (size_t)gi * 4;
        const float* src; short* dst;
        if (off < (size_t)HH * VV) { src = w1 + off; dst = w1b + off; }
        else                       { src = w2 + (off - (size_t)HH * VV); dst = w2b + (off - (size_t)HH * VV); }
        float4 x = *reinterpret_cast<const float4*>(src);
        __hip_bfloat16 c0 = __float2bfloat16(x.x), c1 = __float2bfloat16(x.y),
                       c2 = __float2bfloat16(x.z), c3 = __float2bfloat16(x.w);
        short4 pk;
        pk.x = *reinterpret_cast<short*>(&c0);
        pk.y = *reinterpret_cast<short*>(&c1);
        pk.z = *reinterpret_cast<short*>(&c2);
        pk.w = *reinterpret_cast<short*>(&c3);
        *reinterpret_cast<short4*>(dst) = pk;
    }

    // ---- Phase A: v_bos (block 0, first half) ----
    if (blockIdx.x == 0 && tid < 256) {
        const float4* wp = reinterpret_cast<const float4*>(wo_w + (size_t)tid * VV);
        const float4* vp = reinterpret_cast<const float4*>(wv_bos);
        float acc = 0.f;
        for (int j = 0; j < VV / 4; ++j) {
            float4 a = wp[j], bq = vp[j];
            acc += a.x * bq.x + a.y * bq.y + a.z * bq.z + a.w * bq.w;
        }
        v_bos[tid] = acc;
    }

    __syncthreads();
    chunkSum[((size_t)b * CHK + (n0 >> 5) + half) * VV + t256] =
        lds8[half * 4 + 0][t256] + lds8[half * 4 + 1][t256] +
        lds8[half * 4 + 2][t256] + lds8[half * 4 + 3][t256];

    // ======== grid-wide barrier: all Xb/wpack/chunkSum/w1b/w2b/v_bos ready ====
    __threadfence();
    cg::this_grid().sync();

    // ---- Phase B: fused MLP + chunk-prefix + attention emit ----
    short (*sW1)[64 * 256] = reinterpret_cast<short(*)[64 * 256]>(smem);           // 2 x 32 KB
    short (*sW2)[256 * 64] = reinterpret_cast<short(*)[256 * 64]>(smem + 65536);   // 2 x 32 KB
    short* sY = reinterpret_cast<short*>(smem + 131072);                            // 8 KB

    int wm = wave >> 2, wn = wave & 3;
    int ra = lane & 15, q = lane >> 4;

    auto stage = [&](int hc, int buf) {
#pragma unroll
        for (int it = 0; it < 4; ++it) {
            int g = wave * 4 + it;
            int n = g * 2 + (lane >> 5);
            int slot = lane & 31;
            load_lds16(w1b + (size_t)(hc * 64 + n) * VV + (slot ^ (n & 7)) * 8,
                       &sW1[buf][g * 512]);
        }
#pragma unroll
        for (int it = 0; it < 4; ++it) {
            int g = wave * 4 + it;
            int v = g * 8 + (lane >> 3);
            int slot = lane & 7;
            load_lds16(w2b + (size_t)v * HH + hc * 64 + (slot ^ (v & 7)) * 8,
                       &sW2[buf][g * 512]);
        }
    };

    stage(0, 0);   // start DMA; overlaps with xf loads + prefix below

    // X fragments: rows of this wave's wm-half, full K=256 (own block's rows)
    short8 xf[8][2];
#pragma unroll
    for (int ks = 0; ks < 8; ++ks)
#pragma unroll
        for (int i = 0; i < 2; ++i)
            xf[ks][i] = *reinterpret_cast<const short8*>(
                Xb + (size_t)(m0 + wm * 32 + i * 16 + ra) * VV + ks * 32 + q * 8);

    // exclusive chunk prefix (same c-order as the old chunkscan -> identical)
    int vcol = t256;
    int cpre = (n0 >> 5) + half;
    float Sreg = 0.f;
    {
        const float* cs = chunkSum + (size_t)(b * CHK) * VV + vcol;
#pragma unroll 4
        for (int c2 = 0; c2 < cpre; ++c2) Sreg += cs[(size_t)c2 * VV];
    }

    floatx4 oacc[2][4];
#pragma unroll
    for (int i = 0; i < 2; ++i)
#pragma unroll
        for (int j = 0; j < 4; ++j) oacc[i][j] = floatx4{0.f, 0.f, 0.f, 0.f};

    for (int hc = 0; hc < 16; ++hc) {
        int p = hc & 1;
        __syncthreads();                 // buf[p] staged+visible; sY consumed
        if (hc < 15) stage(hc + 1, p ^ 1);

        // ---- GEMM1: Y[wm*32..+32][wn*16..+16] = X @ w1c^T ----
        floatx4 yacc[2];
        yacc[0] = floatx4{0.f, 0.f, 0.f, 0.f};
        yacc[1] = floatx4{0.f, 0.f, 0.f, 0.f};
        int nb = wn * 16 + ra;
#pragma unroll
        for (int ks = 0; ks < 8; ++ks) {
            short8 bfr = *reinterpret_cast<const short8*>(
                &sW1[p][nb * 256 + (((ks * 4 + q) ^ (ra & 7)) * 8)]);
#pragma unroll
            for (int i = 0; i < 2; ++i)
                yacc[i] = __builtin_amdgcn_mfma_f32_16x16x32_bf16(xf[ks][i], bfr, yacc[i], 0, 0, 0);
        }
        // relu -> bf16 -> sY (swizzled)
#pragma unroll
        for (int i = 0; i < 2; ++i)
#pragma unroll
            for (int reg = 0; reg < 4; ++reg) {
                int mr = wm * 32 + i * 16 + q * 4 + reg;
                int ke = wn * 16 + ra;
                __hip_bfloat16 hb = __float2bfloat16(fmaxf(yacc[i][reg], 0.f));
                sY[mr * 64 + (((ke >> 3) ^ (mr & 7)) * 8) + (ke & 7)] =
                    *reinterpret_cast<short*>(&hb);
            }
        __syncthreads();                 // sY visible

        // ---- GEMM2: oacc[wm*32..+32][wn*64..+64] += Yc @ w2c^T ----
#pragma unroll
        for (int kk = 0; kk < 2; ++kk) {
            short8 a2[2];
#pragma unroll
            for (int i = 0; i < 2; ++i) {
                int mr = wm * 32 + i * 16 + ra;
                a2[i] = *reinterpret_cast<const short8*>(
                    &sY[mr * 64 + (((kk * 4 + q) ^ (ra & 7)) * 8)]);
            }
#pragma unroll
            for (int j = 0; j < 4; ++j) {
                int v = wn * 64 + j * 16 + ra;
                short8 b2 = *reinterpret_cast<const short8*>(
                    &sW2[p][v * 64 + (((kk * 4 + q) ^ (ra & 7)) * 8)]);
#pragma unroll
                for (int i = 0; i < 2; ++i)
                    oacc[i][j] = __builtin_amdgcn_mfma_f32_16x16x32_bf16(a2[i], b2, oacc[i][j], 0, 0, 0);
            }
        }
    }

    // ---- epilogue: stage mlp result to LDS (stride 260 floats) ----
    __syncthreads();                     // all GEMM2 LDS reads done before alias
    float* sOut = reinterpret_cast<float*>(smem);   // 64 x 260 floats = 66.5 KB
#pragma unroll
    for (int i = 0; i < 2; ++i)
#pragma unroll
        for (int j = 0; j < 4; ++j)
#pragma unroll
            for (int reg = 0; reg < 4; ++reg) {
                int l = wm * 32 + i * 16 + q * 4 + reg;
                int col = wn * 64 + j * 16 + ra;
                sOut[l * 260 + col] = oacc[i][j][reg];
            }
    __syncthreads();

    // ---- fused attention emit: out = attn + mlp ----
    {
        int r0 = n0 + half * RPC;
        float wvv = wv[vcol];
        float vb  = v_bos[vcol];
        float S = Sreg;
        float prev = 0.f;
        int r = r0;
        if (r0 == 0) {
            out[((size_t)b * NN) * VV + vcol] = vb + sOut[0 * 260 + vcol];
            r = 1;
        } else {
            short p2 = Xb[((size_t)b * NN + r0 - 1) * VV + vcol];
            prev = bf16s_to_f(p2) * wvv;
        }
#pragma unroll 4
        for (; r < r0 + RPC; ++r) {
            size_t idx = ((size_t)b * NN + r) * VV + vcol;
            float val = bf16s_to_f(Xb[idx]) * wvv;
            S += val;
            float4 wp4 = *reinterpret_cast<const float4*>(wpack + (size_t)(b * NN + r) * 4);
            float o = wp4.x * vb + wp4.y * prev + wp4.z * S;
            prev = val;
            out[idx] = o + sOut[(r - n0) * 260 + vcol];
        }
    }
}

// ---------------------------------------------------------------------------
extern "C" void kernel_launch(void* const* d_in, const int* in_sizes, int n_in,
                              void* d_out, int out_size, void* d_ws, size_t ws_size,
                              hipStream_t stream)
{
    const float* h        = (const float*)d_in[0];
    const float* ln_attn_g = (const float*)d_in[3];
    const float* ln_attn_b = (const float*)d_in[4];
    const float* ln_mlp_g  = (const float*)d_in[5];
    const float* ln_mlp_b  = (const float*)d_in[6];
    const float* wv        = (const float*)d_in[7];
    const float* wv_bos    = (const float*)d_in[8];
    const float* wo_w      = (const float*)d_in[9];
    const float* qk_bos    = (const float*)d_in[10];
    const float* qk_prev   = (const float*)d_in[11];
    const float* qk_dir    = (const float*)d_in[12];
    const float* w1        = (const float*)d_in[13];
    const float* w2        = (const float*)d_in[14];
    float* out = (float*)d_out;

    float* v_bos     = (float*)d_ws;                 // 256
    float* wpack     = v_bos + VV;                   // BB*NN*4 = 65536
    float* chunkSum  = wpack + (size_t)BB * NN * 4;  // BB*CHK*VV = 131072
    short* Xb        = (short*)(chunkSum + BB * CHK * VV);
    short* w1b       = (short*)(Xb + (size_t)BB * NN * VV);
    short* w2b       = w1b + HH * VV;

    void* args[] = {
        (void*)&h, (void*)&ln_attn_g, (void*)&ln_attn_b,
        (void*)&ln_mlp_g, (void*)&ln_mlp_b, (void*)&qk_dir,
        (void*)&wo_w, (void*)&wv_bos, (void*)&wv,
        (void*)&qk_bos, (void*)&qk_prev,
        (void*)&w1, (void*)&w2,
        (void*)&Xb, (void*)&wpack, (void*)&chunkSum, (void*)&v_bos,
        (void*)&w1b, (void*)&w2b, (void*)&out
    };
    hipLaunchCooperativeKernel((const void*)fused_all, dim3(256), dim3(512),
                               args, 0, stream);
}

// Round 4
// 154.329 us; speedup vs baseline: 1.6974x; 1.6974x over previous
//
#include <hip/hip_runtime.h>
#include <hip/hip_bf16.h>

#define BB 8
#define NN 2048
#define VV 256
#define HH 1024
#define CHK 64
#define RPC 32
constexpr float EPS = 1e-5f;

typedef __attribute__((ext_vector_type(4))) float floatx4;
typedef __attribute__((ext_vector_type(8))) short short8;

__device__ __forceinline__ void load_lds16(const void* g, void* l) {
    __builtin_amdgcn_global_load_lds((const __attribute__((address_space(1))) void*)g,
                                     (__attribute__((address_space(3))) void*)l, 16, 0, 0);
}
__device__ __forceinline__ float bf16s_to_f(short s) {
    unsigned u = ((unsigned)(unsigned short)s) << 16;
    return __builtin_bit_cast(float, u);
}

// ---------------------------------------------------------------------------
// K1: fused scan pass (R2 structure, + early row-load hoist).
//   Per block (b, chunk c of 32 rows):
//   - issue the 8 main h row loads FIRST (so the LN's barrier drains overlap
//     useful traffic instead of serializing after it)
//   - redundant in-block LN of h[b,0,:] (attn+mlp) -> s0b, mlp row-0 swap
//   - bf16 convert (BOS swap), packed softmax weights {W0,WP-WZ,WZ,0},
//     chunk partial sums
//   - weight bf16 conversion tail (1 float4/thread exact cover)
//   - block 0: v_bos = wo_w @ wv_bos
// ---------------------------------------------------------------------------
__global__ __launch_bounds__(256) void scan_fused_kernel(
    const float* __restrict__ h,
    const float* __restrict__ g_attn, const float* __restrict__ b_attn,
    const float* __restrict__ g_mlp,  const float* __restrict__ b_mlp,
    const float* __restrict__ qk_dir,
    const float* __restrict__ wo_w,  const float* __restrict__ wv_bos,
    const float* __restrict__ wv,
    const float* __restrict__ qk_bos, const float* __restrict__ qk_prev,
    short* __restrict__ Xb,
    float* __restrict__ wpack,
    float* __restrict__ chunkSum,
    float* __restrict__ v_bos,
    const float* __restrict__ w1, const float* __restrict__ w2,
    short* __restrict__ w1b, short* __restrict__ w2b)
{
    __shared__ float lds[4][VV];
    __shared__ __align__(16) float mrow[VV];
    __shared__ float redA[4], redB[4], redC[4];
    int t = threadIdx.x;
    int wave = t >> 6, lane = t & 63;
    int b = blockIdx.x / CHK, c = blockIdx.x % CHK;
    int r0 = c * RPC + wave * 8;

    // ---- issue main row loads early (independent of LN) ----
    float4 xr[8];
#pragma unroll
    for (int rr = 0; rr < 8; ++rr) {
        size_t base = ((size_t)b * NN + r0 + rr) * VV;
        xr[rr] = *reinterpret_cast<const float4*>(h + base + lane * 4);
    }

    // ---- in-block LN of row 0 (both branches) + s0b ----
    float x0 = h[(size_t)b * NN * VV + t];
    float s = x0;
    for (int off = 32; off > 0; off >>= 1) s += __shfl_down(s, off);
    if (lane == 0) redA[wave] = s;
    __syncthreads();
    float m = (redA[0] + redA[1] + redA[2] + redA[3]) * (1.0f / VV);
    float xc = x0 - m;
    float sv = xc * xc;
    for (int off = 32; off > 0; off >>= 1) sv += __shfl_down(sv, off);
    if (lane == 0) redB[wave] = sv;
    __syncthreads();
    float var = (redB[0] + redB[1] + redB[2] + redB[3]) * (1.0f / VV);
    float inv = 1.0f / sqrtf(var + EPS);
    float an = xc * inv * g_attn[t] + b_attn[t];
    float mn = xc * inv * g_mlp[t]  + b_mlp[t];
    float sd = an * qk_dir[t];
    for (int off = 32; off > 0; off >>= 1) sd += __shfl_down(sd, off);
    if (lane == 0) redC[wave] = sd;
    mrow[t] = mn;
    __syncthreads();
    float s0b = redC[0] + redC[1] + redC[2] + redC[3];

    // ---- main scan over this chunk's 32 rows (8 per wave) ----
    float4 wv4 = reinterpret_cast<const float4*>(wv)[lane];
    float4 qb4 = reinterpret_cast<const float4*>(qk_bos)[lane];
    float4 qp4 = reinterpret_cast<const float4*>(qk_prev)[lane];
    float4 vsum = {0.f, 0.f, 0.f, 0.f};
#pragma unroll
    for (int rr = 0; rr < 8; ++rr) {
        int r = r0 + rr;
        size_t base = ((size_t)b * NN + r) * VV;
        float4 x = xr[rr];
        float4 xs = x;
        if (r == 0) xs = *reinterpret_cast<const float4*>(&mrow[lane * 4]);
        __hip_bfloat16 c0 = __float2bfloat16(xs.x), c1 = __float2bfloat16(xs.y),
                       c2 = __float2bfloat16(xs.z), c3 = __float2bfloat16(xs.w);
        short4 pk;
        pk.x = *reinterpret_cast<short*>(&c0);
        pk.y = *reinterpret_cast<short*>(&c1);
        pk.z = *reinterpret_cast<short*>(&c2);
        pk.w = *reinterpret_cast<short*>(&c3);
        *reinterpret_cast<short4*>(Xb + base + lane * 4) = pk;
        if (r != 0) {
            vsum.x += bf16s_to_f(pk.x) * wv4.x; vsum.y += bf16s_to_f(pk.y) * wv4.y;
            vsum.z += bf16s_to_f(pk.z) * wv4.z; vsum.w += bf16s_to_f(pk.w) * wv4.w;
        }
        float s1 = x.x * qb4.x + x.y * qb4.y + x.z * qb4.z + x.w * qb4.w;
        float s2 = x.x * qp4.x + x.y * qp4.y + x.z * qp4.z + x.w * qp4.w;
        for (int off = 32; off > 0; off >>= 1) {
            s1 += __shfl_down(s1, off);
            s2 += __shfl_down(s2, off);
        }
        if (lane == 0) {
            int gid = b * NN + r;
            float W0, WP, WZ;
            if (r == 0) { W0 = 1.f; WP = 0.f; WZ = 0.f; }
            else if (r == 1) {
                float a = s1 * s0b + s2;
                float mm = fmaxf(a, 0.f);
                float ea = expf(a - mm), ez = expf(-mm);
                float Z = ea + ez;
                W0 = ea / Z; WZ = ez / Z; WP = WZ;
            } else {
                float a = s1 * s0b;
                float mm = fmaxf(fmaxf(a, s2), 0.f);
                float ea = expf(a - mm), ed = expf(s2 - mm), ez = expf(-mm);
                float Z = ea + ed + (float)(r - 1) * ez;
                W0 = ea / Z; WP = ed / Z; WZ = ez / Z;
            }
            float4 wp4 = {W0, WP - WZ, WZ, 0.f};
            *reinterpret_cast<float4*>(wpack + (size_t)gid * 4) = wp4;
        }
    }
    reinterpret_cast<float4*>(lds[wave])[lane] = vsum;

    // ---- fused weight conversion tail ----
    {
        int gi = blockIdx.x * 256 + threadIdx.x;   // float4 index, exact cover
        size_t off = (size_t)gi * 4;
        const float* src; short* dst;
        if (off < (size_t)HH * VV) { src = w1 + off; dst = w1b + off; }
        else                       { src = w2 + (off - (size_t)HH * VV); dst = w2b + (off - (size_t)HH * VV); }
        float4 x = *reinterpret_cast<const float4*>(src);
        __hip_bfloat16 c0 = __float2bfloat16(x.x), c1 = __float2bfloat16(x.y),
                       c2 = __float2bfloat16(x.z), c3 = __float2bfloat16(x.w);
        short4 pk;
        pk.x = *reinterpret_cast<short*>(&c0);
        pk.y = *reinterpret_cast<short*>(&c1);
        pk.z = *reinterpret_cast<short*>(&c2);
        pk.w = *reinterpret_cast<short*>(&c3);
        *reinterpret_cast<short4*>(dst) = pk;
    }

    // ---- block 0: v_bos = wo_w @ wv_bos ----
    if (blockIdx.x == 0) {
        const float4* wp = reinterpret_cast<const float4*>(wo_w + (size_t)t * VV);
        const float4* vp = reinterpret_cast<const float4*>(wv_bos);
        float acc = 0.f;
        for (int j = 0; j < VV / 4; ++j) {
            float4 a = wp[j], bq = vp[j];
            acc += a.x * bq.x + a.y * bq.y + a.z * bq.z + a.w * bq.w;
        }
        v_bos[t] = acc;
    }

    __syncthreads();
    int v = threadIdx.x;
    chunkSum[((size_t)b * CHK + c) * VV + v] = lds[0][v] + lds[1][v] + lds[2][v] + lds[3][v];
}

// ---------------------------------------------------------------------------
// K2: fused MLP + chunk-prefix + attention emit (R2 structure, + counted
//   barrier waits in the hc loop).
//   Key change vs R2: the mid-iteration "sY visible" barrier now waits only
//   lgkmcnt(0) (ds_writes of sY) and does NOT drain vmcnt — the weight-DMA
//   issued at the top of the iteration stays in flight across it and lands
//   any time before the NEXT top barrier's vmcnt(0). This overlaps the
//   ~0.5 µs/iter of L2 weight streaming with GEMM2 + next GEMM1 instead of
//   serializing it (T3/T4 counted-vmcnt principle, applied minimally).
// ---------------------------------------------------------------------------
__global__ __launch_bounds__(512) void mlp_fused6(const short* __restrict__ Xb,
                                                  const short* __restrict__ w1b,
                                                  const short* __restrict__ w2b,
                                                  const float* __restrict__ wv,
                                                  const float* __restrict__ v_bos,
                                                  const float* __restrict__ wpack,
                                                  const float* __restrict__ chunkSum,
                                                  float* __restrict__ out)
{
    __shared__ __align__(16) char smem[136 * 1024];
    short (*sW1)[64 * 256] = reinterpret_cast<short(*)[64 * 256]>(smem);           // 2 x 32 KB
    short (*sW2)[256 * 64] = reinterpret_cast<short(*)[256 * 64]>(smem + 65536);   // 2 x 32 KB
    short* sY = reinterpret_cast<short*>(smem + 131072);                            // 8 KB

    int wave = threadIdx.x >> 6, lane = threadIdx.x & 63;
    int wm = wave >> 2, wn = wave & 3;
    int ra = lane & 15, q = lane >> 4;
    int m0 = blockIdx.x * 64;
    int bq = m0 >> 11;                   // batch index
    int n0 = m0 & (NN - 1);              // row offset within batch

    auto stage = [&](int hc, int buf) {
#pragma unroll
        for (int it = 0; it < 4; ++it) {
            int g = wave * 4 + it;
            int n = g * 2 + (lane >> 5);
            int slot = lane & 31;
            load_lds16(w1b + (size_t)(hc * 64 + n) * VV + (slot ^ (n & 7)) * 8,
                       &sW1[buf][g * 512]);
        }
#pragma unroll
        for (int it = 0; it < 4; ++it) {
            int g = wave * 4 + it;
            int v = g * 8 + (lane >> 3);
            int slot = lane & 7;
            load_lds16(w2b + (size_t)v * HH + hc * 64 + (slot ^ (v & 7)) * 8,
                       &sW2[buf][g * 512]);
        }
    };

    stage(0, 0);   // start DMA early; overlaps with xf loads + prefix below

    // X fragments: rows of this wave's wm-half, full K=256
    short8 xf[8][2];
#pragma unroll
    for (int ks = 0; ks < 8; ++ks)
#pragma unroll
        for (int i = 0; i < 2; ++i)
            xf[ks][i] = *reinterpret_cast<const short8*>(
                Xb + (size_t)(m0 + wm * 32 + i * 16 + ra) * VV + ks * 32 + q * 8);

    // exclusive chunk prefix for the attention emit (same c-order as chunkscan)
    int vcol = threadIdx.x & 255;
    int half = threadIdx.x >> 8;
    int cpre = (n0 >> 5) + half;
    float Sreg = 0.f;
    {
        const float* cs = chunkSum + (size_t)(bq * CHK) * VV + vcol;
#pragma unroll 4
        for (int c2 = 0; c2 < cpre; ++c2) Sreg += cs[(size_t)c2 * VV];
    }

    floatx4 oacc[2][4];
#pragma unroll
    for (int i = 0; i < 2; ++i)
#pragma unroll
        for (int j = 0; j < 4; ++j) oacc[i][j] = floatx4{0.f, 0.f, 0.f, 0.f};

    for (int hc = 0; hc < 16; ++hc) {
        int p = hc & 1;
        // top barrier: buf[p] DMA must be complete (vmcnt(0)), all waves'
        // previous-iteration LDS reads retired (lgkmcnt(0) + barrier).
        __builtin_amdgcn_sched_barrier(0);
        asm volatile("s_waitcnt vmcnt(0) lgkmcnt(0)" ::: "memory");
        __builtin_amdgcn_s_barrier();
        __builtin_amdgcn_sched_barrier(0);
        if (hc < 15) stage(hc + 1, p ^ 1);

        // ---- GEMM1: Y[wm*32..+32][wn*16..+16] = X @ w1c^T ----
        floatx4 yacc[2];
        yacc[0] = floatx4{0.f, 0.f, 0.f, 0.f};
        yacc[1] = floatx4{0.f, 0.f, 0.f, 0.f};
        int nb = wn * 16 + ra;
#pragma unroll
        for (int ks = 0; ks < 8; ++ks) {
            short8 bfr = *reinterpret_cast<const short8*>(
                &sW1[p][nb * 256 + (((ks * 4 + q) ^ (ra & 7)) * 8)]);
#pragma unroll
            for (int i = 0; i < 2; ++i)
                yacc[i] = __builtin_amdgcn_mfma_f32_16x16x32_bf16(xf[ks][i], bfr, yacc[i], 0, 0, 0);
        }
        // relu -> bf16 -> sY (swizzled)
#pragma unroll
        for (int i = 0; i < 2; ++i)
#pragma unroll
            for (int reg = 0; reg < 4; ++reg) {
                int mr = wm * 32 + i * 16 + q * 4 + reg;
                int ke = wn * 16 + ra;
                __hip_bfloat16 hb = __float2bfloat16(fmaxf(yacc[i][reg], 0.f));
                sY[mr * 64 + (((ke >> 3) ^ (mr & 7)) * 8) + (ke & 7)] =
                    *reinterpret_cast<short*>(&hb);
            }
        // mid barrier: sY ds_writes visible. lgkmcnt(0) ONLY — the weight DMA
        // (vmcnt) intentionally stays outstanding until the next top barrier.
        __builtin_amdgcn_sched_barrier(0);
        asm volatile("s_waitcnt lgkmcnt(0)" ::: "memory");
        __builtin_amdgcn_s_barrier();
        __builtin_amdgcn_sched_barrier(0);

        // ---- GEMM2: oacc[wm*32..+32][wn*64..+64] += Yc @ w2c^T ----
#pragma unroll
        for (int kk = 0; kk < 2; ++kk) {
            short8 a2[2];
#pragma unroll
            for (int i = 0; i < 2; ++i) {
                int mr = wm * 32 + i * 16 + ra;
                a2[i] = *reinterpret_cast<const short8*>(
                    &sY[mr * 64 + (((kk * 4 + q) ^ (ra & 7)) * 8)]);
            }
#pragma unroll
            for (int j = 0; j < 4; ++j) {
                int v = wn * 64 + j * 16 + ra;
                short8 b2 = *reinterpret_cast<const short8*>(
                    &sW2[p][v * 64 + (((kk * 4 + q) ^ (ra & 7)) * 8)]);
#pragma unroll
                for (int i = 0; i < 2; ++i)
                    oacc[i][j] = __builtin_amdgcn_mfma_f32_16x16x32_bf16(a2[i], b2, oacc[i][j], 0, 0, 0);
            }
        }
    }

    // ---- epilogue: stage mlp result to LDS (stride 260 floats) ----
    __syncthreads();                     // full drain; all GEMM2 reads done before alias
    float* sOut = reinterpret_cast<float*>(smem);   // 64 x 260 floats = 66.5 KB
#pragma unroll
    for (int i = 0; i < 2; ++i)
#pragma unroll
        for (int j = 0; j < 4; ++j)
#pragma unroll
            for (int reg = 0; reg < 4; ++reg) {
                int l = wm * 32 + i * 16 + q * 4 + reg;
                int col = wn * 64 + j * 16 + ra;
                sOut[l * 260 + col] = oacc[i][j][reg];
            }
    __syncthreads();

    // ---- fused attention emit: out = attn + mlp ----
    {
        int r0 = n0 + half * RPC;
        float wvv = wv[vcol];
        float vb  = v_bos[vcol];
        float S = Sreg;
        float prev = 0.f;
        int r = r0;
        if (r0 == 0) {
            out[((size_t)bq * NN) * VV + vcol] = vb + sOut[0 * 260 + vcol];
            r = 1;
        } else {
            short p2 = Xb[((size_t)bq * NN + r0 - 1) * VV + vcol];
            prev = bf16s_to_f(p2) * wvv;
        }
#pragma unroll 4
        for (; r < r0 + RPC; ++r) {
            size_t idx = ((size_t)bq * NN + r) * VV + vcol;
            float val = bf16s_to_f(Xb[idx]) * wvv;
            S += val;
            float4 wp4 = *reinterpret_cast<const float4*>(wpack + (size_t)(bq * NN + r) * 4);
            float o = wp4.x * vb + wp4.y * prev + wp4.z * S;
            prev = val;
            out[idx] = o + sOut[(r - n0) * 260 + vcol];
        }
    }
}

// ---------------------------------------------------------------------------
extern "C" void kernel_launch(void* const* d_in, const int* in_sizes, int n_in,
                              void* d_out, int out_size, void* d_ws, size_t ws_size,
                              hipStream_t stream)
{
    const float* h        = (const float*)d_in[0];
    const float* ln_attn_g = (const float*)d_in[3];
    const float* ln_attn_b = (const float*)d_in[4];
    const float* ln_mlp_g  = (const float*)d_in[5];
    const float* ln_mlp_b  = (const float*)d_in[6];
    const float* wv        = (const float*)d_in[7];
    const float* wv_bos    = (const float*)d_in[8];
    const float* wo_w      = (const float*)d_in[9];
    const float* qk_bos    = (const float*)d_in[10];
    const float* qk_prev   = (const float*)d_in[11];
    const float* qk_dir    = (const float*)d_in[12];
    const float* w1        = (const float*)d_in[13];
    const float* w2        = (const float*)d_in[14];
    float* out = (float*)d_out;

    float* v_bos     = (float*)d_ws;                 // 256
    float* wpack     = v_bos + VV;                   // BB*NN*4 = 65536
    float* chunkSum  = wpack + (size_t)BB * NN * 4;  // BB*CHK*VV = 131072
    short* Xb        = (short*)(chunkSum + BB * CHK * VV);
    short* w1b       = (short*)(Xb + (size_t)BB * NN * VV);
    short* w2b       = w1b + HH * VV;

    scan_fused_kernel<<<BB * CHK, 256, 0, stream>>>(h, ln_attn_g, ln_attn_b,
                                                    ln_mlp_g, ln_mlp_b, qk_dir,
                                                    wo_w, wv_bos, wv, qk_bos, qk_prev,
                                                    Xb, wpack, chunkSum, v_bos,
                                                    w1, w2, w1b, w2b);
    mlp_fused6<<<256, 512, 0, stream>>>(Xb, w1b, w2b, wv, v_bos, wpack, chunkSum, out);
}